// Round 13
// baseline (211.165 us; speedup 1.0000x reference)
//
#include <hip/hip_runtime.h>
#include <hip/hip_fp16.h>
#include <math.h>

#define DHID 128
#define DOUT 64
#define EPB 4096          // edges per binning block
#define BUCK_SH 8         // 256 nodes per bucket

typedef _Float16 half8 __attribute__((ext_vector_type(8)));
typedef float f32x4 __attribute__((ext_vector_type(4)));

static inline size_t align_up(size_t v, size_t a) { return (v + a - 1) / a * a; }

// ============ fused: bincount (blocks 0..nblka-1) + weight prep (blocks nblka..) ============
__global__ __launch_bounds__(256) void k_prep(const int* __restrict__ src, int* __restrict__ dir,
                                              int* __restrict__ btot, int E, int nbuck, int nblka,
                                              const float* __restrict__ W1, const float* __restrict__ W2,
                                              _Float16* __restrict__ Wt1, _Float16* __restrict__ Wt2) {
    __shared__ int hist[512];
    int tid = threadIdx.x;
    int blk = blockIdx.x;
    if (blk < nblka) {
        for (int i = tid; i < nbuck; i += 256) hist[i] = 0;
        __syncthreads();
        int e0 = blk * EPB;
        #pragma unroll
        for (int j = 0; j < EPB / 256; ++j) {
            int e = e0 + tid + j * 256;
            if (e < E) atomicAdd(&hist[src[e] >> BUCK_SH], 1);
        }
        __syncthreads();
        for (int i = tid; i < nbuck; i += 256) {
            int c = hist[i];
            dir[i * nblka + blk] = c;
            if (c) atomicAdd(&btot[i], c);
        }
    } else {
        int b = blk - nblka;   // 0..95
        if (b < 64) {
            int m = b * 256 + tid;
            int c = m >> 7, k = m & 127;
            Wt1[m] = (_Float16)W1[(size_t)k * 128 + c];
        } else {
            int m = (b - 64) * 256 + tid;
            int c = m >> 7, k = m & 127;
            Wt2[m] = (_Float16)W2[(size_t)k * 64 + c];
        }
    }
}

// ============ fused: GEMM1 (blocks 0..ng1-1) + dirscan (blocks ng1..) ============
__global__ __launch_bounds__(256) void k_g1ds(const float* __restrict__ x, const _Float16* __restrict__ Wt1,
                                              __half* __restrict__ xw, int n, int ng1,
                                              int* __restrict__ dir, const int* __restrict__ btot,
                                              int* __restrict__ bucketbase, int* __restrict__ off,
                                              int nbuck, int nblka, int E) {
    __shared__ _Float16 Ws[128 * 128];    // 32 KB (gemm1 role)
    __shared__ int h[512], s4[128], redb[256];
    int tid = threadIdx.x;
    if (blockIdx.x < ng1) {
        int row0 = blockIdx.x * 64;
        #pragma unroll
        for (int m0 = 0; m0 < 2048; m0 += 256) {
            int m = tid + m0;
            int c = m >> 4, kq = m & 15;
            uint4 v = *(const uint4*)(Wt1 + (size_t)m * 8);
            int byte = (c * 256 + kq * 16) ^ ((c & 7) << 4);
            *(uint4*)((char*)Ws + byte) = v;
        }
        __syncthreads();

        int lane = tid & 63;
        int wid = tid >> 6;
        int rg = row0 + wid * 16 + (lane & 15); if (rg >= n) rg = n - 1;
        int kgrp = (lane >> 4) * 8;

        f32x4 acc[8];
        #pragma unroll
        for (int t = 0; t < 8; ++t) acc[t] = (f32x4){0.f, 0.f, 0.f, 0.f};

        #pragma unroll
        for (int kk = 0; kk < 128; kk += 32) {
            int ks = kk + kgrp;
            const float4* xp = (const float4*)(x + (size_t)rg * 128 + ks);
            float4 f0 = xp[0], f1 = xp[1];
            half8 a;
            a[0] = (_Float16)f0.x; a[1] = (_Float16)f0.y; a[2] = (_Float16)f0.z; a[3] = (_Float16)f0.w;
            a[4] = (_Float16)f1.x; a[5] = (_Float16)f1.y; a[6] = (_Float16)f1.z; a[7] = (_Float16)f1.w;
            #pragma unroll
            for (int t = 0; t < 8; ++t) {
                int c = t * 16 + (lane & 15);
                int bbyte = (c * 256 + ks * 2) ^ ((c & 7) << 4);
                half8 b = *(const half8*)((const char*)Ws + bbyte);
                acc[t] = __builtin_amdgcn_mfma_f32_16x16x32_f16(a, b, acc[t], 0, 0, 0);
            }
        }

        #pragma unroll
        for (int t = 0; t < 8; ++t) {
            int c = t * 16 + (lane & 15);
            #pragma unroll
            for (int j = 0; j < 4; ++j) {
                int rs = row0 + wid * 16 + (lane >> 4) * 4 + j;
                if (rs < n) xw[(size_t)rs * 128 + c] = __float2half(acc[t][j]);
            }
        }
    } else {
        int b = blockIdx.x - ng1;   // bucket index
        int s = 0;
        for (int i = tid; i < b; i += 256) s += btot[i];
        redb[tid] = s; __syncthreads();
        #pragma unroll
        for (int d = 128; d > 0; d >>= 1) {
            if (tid < d) redb[tid] += redb[tid + d];
            __syncthreads();
        }
        int base = redb[0];
        if (tid == 0) {
            bucketbase[b] = base;
            if (b == 0) off[n] = E;
            if (b == nbuck - 1) bucketbase[nbuck] = E;
        }
        for (int j = tid; j < nblka; j += 256) h[j] = dir[b * nblka + j];
        __syncthreads();
        int nq = (nblka + 3) >> 2;
        if (tid < nq) {
            int t = 0;
            #pragma unroll
            for (int j = 0; j < 4; ++j) { int idx = tid * 4 + j; if (idx < nblka) t += h[idx]; }
            s4[tid] = t;
        }
        __syncthreads();
        if (tid == 0) { int run = 0; for (int i = 0; i < nq; ++i) { int t = s4[i]; s4[i] = run; run += t; } }
        __syncthreads();
        if (tid < nq) {
            int run = s4[tid] + base;
            #pragma unroll
            for (int j = 0; j < 4; ++j) {
                int idx = tid * 4 + j;
                if (idx < nblka) { int t = h[idx]; dir[b * nblka + idx] = run; run += t; }
            }
        }
    }
}

__global__ __launch_bounds__(256) void k_binwrite(const int* __restrict__ src, const int* __restrict__ dst,
                                                  const float* __restrict__ val, const int* __restrict__ dir,
                                                  int2* __restrict__ ctmp, int E, int nbuck, int nblka) {
    __shared__ int cur[512];
    int tid = threadIdx.x, blk = blockIdx.x;
    for (int i = tid; i < nbuck; i += 256) cur[i] = dir[i * nblka + blk];
    __syncthreads();
    int e0 = blk * EPB;
    #pragma unroll
    for (int j = 0; j < EPB / 256; ++j) {
        int e = e0 + tid + j * 256;
        if (e < E) {
            int s = src[e];
            int bk = s >> BUCK_SH;
            int p = atomicAdd(&cur[bk], 1);
            ctmp[p] = make_int2(((s & 255) << 17) | dst[e], __float_as_int(val[e]));
        }
    }
}

__global__ __launch_bounds__(256) void k_csrify(const int* __restrict__ bucketbase,
                                                const int2* __restrict__ ctmp, int2* __restrict__ cpair,
                                                int* __restrict__ off, int n) {
    __shared__ int h[256], loff[256], cur[256], s4[64];
    int tid = threadIdx.x, b = blockIdx.x;
    int base = bucketbase[b];
    int cnt = bucketbase[b + 1] - base;
    h[tid] = 0;
    __syncthreads();
    for (int i = tid; i < cnt; i += 256) atomicAdd(&h[ctmp[base + i].x >> 17], 1);
    __syncthreads();
    if (tid < 64) {
        int s = 0;
        #pragma unroll
        for (int j = 0; j < 4; ++j) s += h[tid * 4 + j];
        s4[tid] = s;
    }
    __syncthreads();
    if (tid == 0) { int run = 0; for (int i = 0; i < 64; ++i) { int t = s4[i]; s4[i] = run; run += t; } }
    __syncthreads();
    if (tid < 64) {
        int run = s4[tid];
        #pragma unroll
        for (int j = 0; j < 4; ++j) { int idx = tid * 4 + j; loff[idx] = run; run += h[idx]; }
    }
    __syncthreads();
    int node0 = b << BUCK_SH;
    int nodes_b = n - node0; if (nodes_b > 256) nodes_b = 256;
    if (tid < nodes_b) off[node0 + tid] = base + loff[tid];
    cur[tid] = loff[tid];
    __syncthreads();
    for (int i = tid; i < cnt; i += 256) {
        int2 v = ctmp[base + i];
        int sl = v.x >> 17;
        int p = atomicAdd(&cur[sl], 1);
        cpair[base + p] = make_int2(v.x & 0x1FFFF, v.y);
    }
}

// ---------------- GEMM2 (MFMA): hw = fp16(h1 @ W2), h1 fp16 in ----------------
__global__ __launch_bounds__(256) void k_gemm2(const __half* __restrict__ h1, const _Float16* __restrict__ Wt2,
                                               __half* __restrict__ hw, int n) {
    __shared__ _Float16 Ws[64 * 128];     // 16 KB
    int tid = threadIdx.x;
    int row0 = blockIdx.x * 64;

    #pragma unroll
    for (int m0 = 0; m0 < 1024; m0 += 256) {
        int m = tid + m0;
        int c = m >> 4, kq = m & 15;
        uint4 v = *(const uint4*)(Wt2 + (size_t)m * 8);
        int byte = (c * 256 + kq * 16) ^ ((c & 7) << 4);
        *(uint4*)((char*)Ws + byte) = v;
    }
    __syncthreads();

    int lane = tid & 63;
    int wid = tid >> 6;
    int rg = row0 + wid * 16 + (lane & 15); if (rg >= n) rg = n - 1;
    int kgrp = (lane >> 4) * 8;

    f32x4 acc[4];
    #pragma unroll
    for (int t = 0; t < 4; ++t) acc[t] = (f32x4){0.f, 0.f, 0.f, 0.f};

    #pragma unroll
    for (int kk = 0; kk < 128; kk += 32) {
        int ks = kk + kgrp;
        half8 a = *(const half8*)((const void*)(h1 + (size_t)rg * 128 + ks));
        #pragma unroll
        for (int t = 0; t < 4; ++t) {
            int c = t * 16 + (lane & 15);
            int bbyte = (c * 256 + ks * 2) ^ ((c & 7) << 4);
            half8 b = *(const half8*)((const char*)Ws + bbyte);
            acc[t] = __builtin_amdgcn_mfma_f32_16x16x32_f16(a, b, acc[t], 0, 0, 0);
        }
    }

    #pragma unroll
    for (int t = 0; t < 4; ++t) {
        int c = t * 16 + (lane & 15);
        #pragma unroll
        for (int j = 0; j < 4; ++j) {
            int rs = row0 + wid * 16 + (lane >> 4) * 4 + j;
            if (rs < n) hw[(size_t)rs * 64 + c] = __float2half(acc[t][j]);
        }
    }
}

// --------- agg1: LDS-staged edge pairs (nt) + 8-deep gather unroll; nt h1 store ---------
__global__ __launch_bounds__(256) void k_agg1(const __half* __restrict__ xw, const int* __restrict__ off,
                                              const int2* __restrict__ cpair,
                                              __half* __restrict__ h1, int n) {
    __shared__ int2 pbuf[4][64];
    int wave = threadIdx.x >> 6;
    int lane = threadIdx.x & 63;
    int node = blockIdx.x * 4 + wave;
    if (node >= n) return;
    int s = off[node], e = off[node + 1];
    float ax = 0.f, ay = 0.f;
    for (int c0 = s; c0 < e; c0 += 64) {
        int cnt = e - c0; if (cnt > 64) cnt = 64;
        if (lane < cnt) {
            long long pk = __builtin_nontemporal_load((const long long*)(cpair + c0 + lane));
            pbuf[wave][lane] = make_int2((int)(pk & 0xFFFFFFFFLL), (int)(pk >> 32));
        }
        int j = 0;
        for (; j + 8 <= cnt; j += 8) {
            int2 p[8];
            #pragma unroll
            for (int t = 0; t < 8; ++t) p[t] = pbuf[wave][j + t];
            float2 v[8];
            #pragma unroll
            for (int t = 0; t < 8; ++t)
                v[t] = __half22float2(((const __half2*)(xw + (size_t)p[t].x * 128))[lane]);
            #pragma unroll
            for (int t = 0; t < 8; ++t) {
                float w = __int_as_float(p[t].y);
                ax += w * v[t].x; ay += w * v[t].y;
            }
        }
        for (; j < cnt; ++j) {
            int2 p = pbuf[wave][j];
            float w = __int_as_float(p.y);
            float2 v = __half22float2(((const __half2*)(xw + (size_t)p.x * 128))[lane]);
            ax += w * v.x; ay += w * v.y;
        }
    }
    __half2 hv = __floats2half2_rn(fmaxf(ax, 0.f), fmaxf(ay, 0.f));
    unsigned u = *(unsigned*)&hv;
    __builtin_nontemporal_store(u, (unsigned*)(h1 + (size_t)node * 128) + lane);
}

// ------- agg2 + relu + softmax: LDS-staged pairs (nt), fp16 gather, nt out store -------
__global__ __launch_bounds__(256) void k_agg2(const __half* __restrict__ hw, const int* __restrict__ off,
                                              const int2* __restrict__ cpair,
                                              float* __restrict__ out, int n) {
    __shared__ int2 pbuf[4][64];
    int wave = threadIdx.x >> 6;
    int lane = threadIdx.x & 63;
    int node = blockIdx.x * 4 + wave;
    if (node >= n) return;
    int s = off[node], e = off[node + 1];
    float acc = 0.f;
    for (int c0 = s; c0 < e; c0 += 64) {
        int cnt = e - c0; if (cnt > 64) cnt = 64;
        if (lane < cnt) {
            long long pk = __builtin_nontemporal_load((const long long*)(cpair + c0 + lane));
            pbuf[wave][lane] = make_int2((int)(pk & 0xFFFFFFFFLL), (int)(pk >> 32));
        }
        int j = 0;
        for (; j + 8 <= cnt; j += 8) {
            int2 p[8];
            #pragma unroll
            for (int t = 0; t < 8; ++t) p[t] = pbuf[wave][j + t];
            float v[8];
            #pragma unroll
            for (int t = 0; t < 8; ++t)
                v[t] = __half2float(hw[(size_t)p[t].x * 64 + lane]);
            #pragma unroll
            for (int t = 0; t < 8; ++t)
                acc += __int_as_float(p[t].y) * v[t];
        }
        for (; j < cnt; ++j) {
            int2 p = pbuf[wave][j];
            acc += __int_as_float(p.y) * __half2float(hw[(size_t)p.x * 64 + lane]);
        }
    }
    acc = fmaxf(acc, 0.f);
    float m = acc;
    #pragma unroll
    for (int o = 32; o > 0; o >>= 1) m = fmaxf(m, __shfl_xor(m, o));
    float ex = expf(acc - m);
    float sum = ex;
    #pragma unroll
    for (int o = 32; o > 0; o >>= 1) sum += __shfl_xor(sum, o);
    __builtin_nontemporal_store(ex / sum, out + (size_t)node * 64 + lane);
}

extern "C" void kernel_launch(void* const* d_in, const int* in_sizes, int n_in,
                              void* d_out, int out_size, void* d_ws, size_t ws_size,
                              hipStream_t stream) {
    const float* x = (const float*)d_in[0];
    const float* W1 = (const float*)d_in[1];
    const float* W2 = (const float*)d_in[2];
    const int* esrc = (const int*)d_in[3];
    const int* edst = (const int*)d_in[4];
    const float* evalv = (const float*)d_in[5];
    int n = in_sizes[0] / DHID;   // 100000
    int E = in_sizes[3];          // 1,700,000

    int nbuck = (n + 255) >> BUCK_SH;        // 391
    int nblka = (E + EPB - 1) / EPB;         // 416
    int ng1 = (n + 63) / 64;                 // 1563

    char* p = (char*)d_ws;
    int* off = (int*)p;        p += align_up((size_t)(n + 1) * 4, 256);
    int* bucketbase = (int*)p; p += align_up((size_t)(nbuck + 1) * 4, 256);
    int* btot = (int*)p;       p += align_up((size_t)nbuck * 4, 256);
    int* dir = (int*)p;        p += align_up((size_t)nbuck * nblka * 4, 256);
    int2* ctmp = (int2*)p;     p += align_up((size_t)E * 8, 256);
    int2* cpair = (int2*)p;    p += align_up((size_t)E * 8, 256);
    _Float16* Wt1 = (_Float16*)p; p += align_up((size_t)128 * 128 * 2, 256);
    _Float16* Wt2 = (_Float16*)p; p += align_up((size_t)64 * 128 * 2, 256);
    __half* xw = (__half*)p;   p += align_up((size_t)n * DHID * 2, 256);
    __half* h1 = (__half*)p;   p += align_up((size_t)n * DHID * 2, 256);
    __half* hw2 = xw;  // reuse: xw dead after agg1 (hw needs n*64*2 <= n*128*2)

    hipMemsetAsync(btot, 0, (size_t)nbuck * 4, stream);
    k_prep<<<nblka + 96, 256, 0, stream>>>(esrc, dir, btot, E, nbuck, nblka, W1, W2, Wt1, Wt2);
    k_g1ds<<<ng1 + nbuck, 256, 0, stream>>>(x, Wt1, xw, n, ng1, dir, btot, bucketbase, off,
                                            nbuck, nblka, E);
    k_binwrite<<<nblka, 256, 0, stream>>>(esrc, edst, evalv, dir, ctmp, E, nbuck, nblka);
    k_csrify<<<nbuck, 256, 0, stream>>>(bucketbase, ctmp, cpair, off, n);
    k_agg1<<<(n + 3) / 4, 256, 0, stream>>>(xw, off, cpair, h1, n);
    k_gemm2<<<(n + 63) / 64, 256, 0, stream>>>(h1, Wt2, hw2, n);
    k_agg2<<<(n + 3) / 4, 256, 0, stream>>>(hw2, off, cpair, (float*)d_out, n);
}

// Round 14
// 203.731 us; speedup vs baseline: 1.0365x; 1.0365x over previous
//
#include <hip/hip_runtime.h>
#include <hip/hip_fp16.h>
#include <math.h>

#define DHID 128
#define DOUT 64
#define EPB 4096          // edges per binning block
#define BUCK_SH 8         // 256 nodes per bucket

typedef _Float16 half8 __attribute__((ext_vector_type(8)));
typedef float f32x4 __attribute__((ext_vector_type(4)));

static inline size_t align_up(size_t v, size_t a) { return (v + a - 1) / a * a; }

// ============ fused: bincount (blocks 0..nblka-1) + weight prep (blocks nblka..) ============
__global__ __launch_bounds__(256) void k_prep(const int* __restrict__ src, int* __restrict__ dir,
                                              int* __restrict__ btot, int E, int nbuck, int nblka,
                                              const float* __restrict__ W1, const float* __restrict__ W2,
                                              _Float16* __restrict__ Wt1, _Float16* __restrict__ Wt2) {
    __shared__ int hist[512];
    int tid = threadIdx.x;
    int blk = blockIdx.x;
    if (blk < nblka) {
        for (int i = tid; i < nbuck; i += 256) hist[i] = 0;
        __syncthreads();
        int e0 = blk * EPB;
        #pragma unroll
        for (int j = 0; j < EPB / 256; ++j) {
            int e = e0 + tid + j * 256;
            if (e < E) atomicAdd(&hist[src[e] >> BUCK_SH], 1);
        }
        __syncthreads();
        for (int i = tid; i < nbuck; i += 256) {
            int c = hist[i];
            dir[i * nblka + blk] = c;
            if (c) atomicAdd(&btot[i], c);
        }
    } else {
        int b = blk - nblka;   // 0..95
        if (b < 64) {
            int m = b * 256 + tid;
            int c = m >> 7, k = m & 127;
            Wt1[m] = (_Float16)W1[(size_t)k * 128 + c];
        } else {
            int m = (b - 64) * 256 + tid;
            int c = m >> 7, k = m & 127;
            Wt2[m] = (_Float16)W2[(size_t)k * 64 + c];
        }
    }
}

// ============ fused: GEMM1 (blocks 0..ng1-1) + dirscan (blocks ng1..) ============
__global__ __launch_bounds__(256) void k_g1ds(const float* __restrict__ x, const _Float16* __restrict__ Wt1,
                                              __half* __restrict__ xw, int n, int ng1,
                                              int* __restrict__ dir, const int* __restrict__ btot,
                                              int* __restrict__ bucketbase, int* __restrict__ off,
                                              int nbuck, int nblka, int E) {
    __shared__ _Float16 Ws[128 * 128];    // 32 KB (gemm1 role)
    __shared__ int h[512], s4[128], redb[256];
    int tid = threadIdx.x;
    if (blockIdx.x < ng1) {
        int row0 = blockIdx.x * 64;
        #pragma unroll
        for (int m0 = 0; m0 < 2048; m0 += 256) {
            int m = tid + m0;
            int c = m >> 4, kq = m & 15;
            uint4 v = *(const uint4*)(Wt1 + (size_t)m * 8);
            int byte = (c * 256 + kq * 16) ^ ((c & 7) << 4);
            *(uint4*)((char*)Ws + byte) = v;
        }
        __syncthreads();

        int lane = tid & 63;
        int wid = tid >> 6;
        int rg = row0 + wid * 16 + (lane & 15); if (rg >= n) rg = n - 1;
        int kgrp = (lane >> 4) * 8;

        f32x4 acc[8];
        #pragma unroll
        for (int t = 0; t < 8; ++t) acc[t] = (f32x4){0.f, 0.f, 0.f, 0.f};

        #pragma unroll
        for (int kk = 0; kk < 128; kk += 32) {
            int ks = kk + kgrp;
            const float4* xp = (const float4*)(x + (size_t)rg * 128 + ks);
            float4 f0 = xp[0], f1 = xp[1];
            half8 a;
            a[0] = (_Float16)f0.x; a[1] = (_Float16)f0.y; a[2] = (_Float16)f0.z; a[3] = (_Float16)f0.w;
            a[4] = (_Float16)f1.x; a[5] = (_Float16)f1.y; a[6] = (_Float16)f1.z; a[7] = (_Float16)f1.w;
            #pragma unroll
            for (int t = 0; t < 8; ++t) {
                int c = t * 16 + (lane & 15);
                int bbyte = (c * 256 + ks * 2) ^ ((c & 7) << 4);
                half8 b = *(const half8*)((const char*)Ws + bbyte);
                acc[t] = __builtin_amdgcn_mfma_f32_16x16x32_f16(a, b, acc[t], 0, 0, 0);
            }
        }

        #pragma unroll
        for (int t = 0; t < 8; ++t) {
            int c = t * 16 + (lane & 15);
            #pragma unroll
            for (int j = 0; j < 4; ++j) {
                int rs = row0 + wid * 16 + (lane >> 4) * 4 + j;
                if (rs < n) xw[(size_t)rs * 128 + c] = __float2half(acc[t][j]);
            }
        }
    } else {
        int b = blockIdx.x - ng1;   // bucket index
        int s = 0;
        for (int i = tid; i < b; i += 256) s += btot[i];
        redb[tid] = s; __syncthreads();
        #pragma unroll
        for (int d = 128; d > 0; d >>= 1) {
            if (tid < d) redb[tid] += redb[tid + d];
            __syncthreads();
        }
        int base = redb[0];
        if (tid == 0) {
            bucketbase[b] = base;
            if (b == 0) off[n] = E;
            if (b == nbuck - 1) bucketbase[nbuck] = E;
        }
        for (int j = tid; j < nblka; j += 256) h[j] = dir[b * nblka + j];
        __syncthreads();
        int nq = (nblka + 3) >> 2;
        if (tid < nq) {
            int t = 0;
            #pragma unroll
            for (int j = 0; j < 4; ++j) { int idx = tid * 4 + j; if (idx < nblka) t += h[idx]; }
            s4[tid] = t;
        }
        __syncthreads();
        if (tid == 0) { int run = 0; for (int i = 0; i < nq; ++i) { int t = s4[i]; s4[i] = run; run += t; } }
        __syncthreads();
        if (tid < nq) {
            int run = s4[tid] + base;
            #pragma unroll
            for (int j = 0; j < 4; ++j) {
                int idx = tid * 4 + j;
                if (idx < nblka) { int t = h[idx]; dir[b * nblka + idx] = run; run += t; }
            }
        }
    }
}

__global__ __launch_bounds__(256) void k_binwrite(const int* __restrict__ src, const int* __restrict__ dst,
                                                  const float* __restrict__ val, const int* __restrict__ dir,
                                                  int2* __restrict__ ctmp, int E, int nbuck, int nblka) {
    __shared__ int cur[512];
    int tid = threadIdx.x, blk = blockIdx.x;
    for (int i = tid; i < nbuck; i += 256) cur[i] = dir[i * nblka + blk];
    __syncthreads();
    int e0 = blk * EPB;
    #pragma unroll
    for (int j = 0; j < EPB / 256; ++j) {
        int e = e0 + tid + j * 256;
        if (e < E) {
            int s = src[e];
            int bk = s >> BUCK_SH;
            int p = atomicAdd(&cur[bk], 1);
            ctmp[p] = make_int2(((s & 255) << 17) | dst[e], __float_as_int(val[e]));
        }
    }
}

__global__ __launch_bounds__(256) void k_csrify(const int* __restrict__ bucketbase,
                                                const int2* __restrict__ ctmp, int2* __restrict__ cpair,
                                                int* __restrict__ off, int n) {
    __shared__ int h[256], loff[256], cur[256], s4[64];
    int tid = threadIdx.x, b = blockIdx.x;
    int base = bucketbase[b];
    int cnt = bucketbase[b + 1] - base;
    h[tid] = 0;
    __syncthreads();
    for (int i = tid; i < cnt; i += 256) atomicAdd(&h[ctmp[base + i].x >> 17], 1);
    __syncthreads();
    if (tid < 64) {
        int s = 0;
        #pragma unroll
        for (int j = 0; j < 4; ++j) s += h[tid * 4 + j];
        s4[tid] = s;
    }
    __syncthreads();
    if (tid == 0) { int run = 0; for (int i = 0; i < 64; ++i) { int t = s4[i]; s4[i] = run; run += t; } }
    __syncthreads();
    if (tid < 64) {
        int run = s4[tid];
        #pragma unroll
        for (int j = 0; j < 4; ++j) { int idx = tid * 4 + j; loff[idx] = run; run += h[idx]; }
    }
    __syncthreads();
    int node0 = b << BUCK_SH;
    int nodes_b = n - node0; if (nodes_b > 256) nodes_b = 256;
    if (tid < nodes_b) off[node0 + tid] = base + loff[tid];
    cur[tid] = loff[tid];
    __syncthreads();
    for (int i = tid; i < cnt; i += 256) {
        int2 v = ctmp[base + i];
        int sl = v.x >> 17;
        int p = atomicAdd(&cur[sl], 1);
        cpair[base + p] = make_int2(v.x & 0x1FFFF, v.y);
    }
}

// ---------------- GEMM2 (MFMA): hw = fp16(h1 @ W2), h1 fp16 in ----------------
__global__ __launch_bounds__(256) void k_gemm2(const __half* __restrict__ h1, const _Float16* __restrict__ Wt2,
                                               __half* __restrict__ hw, int n) {
    __shared__ _Float16 Ws[64 * 128];     // 16 KB
    int tid = threadIdx.x;
    int row0 = blockIdx.x * 64;

    #pragma unroll
    for (int m0 = 0; m0 < 1024; m0 += 256) {
        int m = tid + m0;
        int c = m >> 4, kq = m & 15;
        uint4 v = *(const uint4*)(Wt2 + (size_t)m * 8);
        int byte = (c * 256 + kq * 16) ^ ((c & 7) << 4);
        *(uint4*)((char*)Ws + byte) = v;
    }
    __syncthreads();

    int lane = tid & 63;
    int wid = tid >> 6;
    int rg = row0 + wid * 16 + (lane & 15); if (rg >= n) rg = n - 1;
    int kgrp = (lane >> 4) * 8;

    f32x4 acc[4];
    #pragma unroll
    for (int t = 0; t < 4; ++t) acc[t] = (f32x4){0.f, 0.f, 0.f, 0.f};

    #pragma unroll
    for (int kk = 0; kk < 128; kk += 32) {
        int ks = kk + kgrp;
        half8 a = *(const half8*)((const void*)(h1 + (size_t)rg * 128 + ks));
        #pragma unroll
        for (int t = 0; t < 4; ++t) {
            int c = t * 16 + (lane & 15);
            int bbyte = (c * 256 + ks * 2) ^ ((c & 7) << 4);
            half8 b = *(const half8*)((const char*)Ws + bbyte);
            acc[t] = __builtin_amdgcn_mfma_f32_16x16x32_f16(a, b, acc[t], 0, 0, 0);
        }
    }

    #pragma unroll
    for (int t = 0; t < 4; ++t) {
        int c = t * 16 + (lane & 15);
        #pragma unroll
        for (int j = 0; j < 4; ++j) {
            int rs = row0 + wid * 16 + (lane >> 4) * 4 + j;
            if (rs < n) hw[(size_t)rs * 64 + c] = __float2half(acc[t][j]);
        }
    }
}

// --------- agg1: LDS-staged edge pairs + 8-deep gather unroll ---------
__global__ __launch_bounds__(256) void k_agg1(const __half* __restrict__ xw, const int* __restrict__ off,
                                              const int2* __restrict__ cpair,
                                              __half* __restrict__ h1, int n) {
    __shared__ int2 pbuf[4][64];
    int wave = threadIdx.x >> 6;
    int lane = threadIdx.x & 63;
    int node = blockIdx.x * 4 + wave;
    if (node >= n) return;
    int s = off[node], e = off[node + 1];
    float ax = 0.f, ay = 0.f;
    for (int c0 = s; c0 < e; c0 += 64) {
        int cnt = e - c0; if (cnt > 64) cnt = 64;
        if (lane < cnt) pbuf[wave][lane] = cpair[c0 + lane];
        int j = 0;
        for (; j + 8 <= cnt; j += 8) {
            int2 p[8];
            #pragma unroll
            for (int t = 0; t < 8; ++t) p[t] = pbuf[wave][j + t];
            float2 v[8];
            #pragma unroll
            for (int t = 0; t < 8; ++t)
                v[t] = __half22float2(((const __half2*)(xw + (size_t)p[t].x * 128))[lane]);
            #pragma unroll
            for (int t = 0; t < 8; ++t) {
                float w = __int_as_float(p[t].y);
                ax += w * v[t].x; ay += w * v[t].y;
            }
        }
        for (; j < cnt; ++j) {
            int2 p = pbuf[wave][j];
            float w = __int_as_float(p.y);
            float2 v = __half22float2(((const __half2*)(xw + (size_t)p.x * 128))[lane]);
            ax += w * v.x; ay += w * v.y;
        }
    }
    ((__half2*)(h1 + (size_t)node * 128))[lane] = __floats2half2_rn(fmaxf(ax, 0.f), fmaxf(ay, 0.f));
}

// ------- agg2 + relu + softmax: LDS-staged pairs, fp16 gather -------
__global__ __launch_bounds__(256) void k_agg2(const __half* __restrict__ hw, const int* __restrict__ off,
                                              const int2* __restrict__ cpair,
                                              float* __restrict__ out, int n) {
    __shared__ int2 pbuf[4][64];
    int wave = threadIdx.x >> 6;
    int lane = threadIdx.x & 63;
    int node = blockIdx.x * 4 + wave;
    if (node >= n) return;
    int s = off[node], e = off[node + 1];
    float acc = 0.f;
    for (int c0 = s; c0 < e; c0 += 64) {
        int cnt = e - c0; if (cnt > 64) cnt = 64;
        if (lane < cnt) pbuf[wave][lane] = cpair[c0 + lane];
        int j = 0;
        for (; j + 8 <= cnt; j += 8) {
            int2 p[8];
            #pragma unroll
            for (int t = 0; t < 8; ++t) p[t] = pbuf[wave][j + t];
            float v[8];
            #pragma unroll
            for (int t = 0; t < 8; ++t)
                v[t] = __half2float(hw[(size_t)p[t].x * 64 + lane]);
            #pragma unroll
            for (int t = 0; t < 8; ++t)
                acc += __int_as_float(p[t].y) * v[t];
        }
        for (; j < cnt; ++j) {
            int2 p = pbuf[wave][j];
            acc += __int_as_float(p.y) * __half2float(hw[(size_t)p.x * 64 + lane]);
        }
    }
    acc = fmaxf(acc, 0.f);
    float m = acc;
    #pragma unroll
    for (int o = 32; o > 0; o >>= 1) m = fmaxf(m, __shfl_xor(m, o));
    float ex = expf(acc - m);
    float sum = ex;
    #pragma unroll
    for (int o = 32; o > 0; o >>= 1) sum += __shfl_xor(sum, o);
    out[(size_t)node * 64 + lane] = ex / sum;
}

extern "C" void kernel_launch(void* const* d_in, const int* in_sizes, int n_in,
                              void* d_out, int out_size, void* d_ws, size_t ws_size,
                              hipStream_t stream) {
    const float* x = (const float*)d_in[0];
    const float* W1 = (const float*)d_in[1];
    const float* W2 = (const float*)d_in[2];
    const int* esrc = (const int*)d_in[3];
    const int* edst = (const int*)d_in[4];
    const float* evalv = (const float*)d_in[5];
    int n = in_sizes[0] / DHID;   // 100000
    int E = in_sizes[3];          // 1,700,000

    int nbuck = (n + 255) >> BUCK_SH;        // 391
    int nblka = (E + EPB - 1) / EPB;         // 416
    int ng1 = (n + 63) / 64;                 // 1563

    char* p = (char*)d_ws;
    int* off = (int*)p;        p += align_up((size_t)(n + 1) * 4, 256);
    int* bucketbase = (int*)p; p += align_up((size_t)(nbuck + 1) * 4, 256);
    int* btot = (int*)p;       p += align_up((size_t)nbuck * 4, 256);
    int* dir = (int*)p;        p += align_up((size_t)nbuck * nblka * 4, 256);
    int2* ctmp = (int2*)p;     p += align_up((size_t)E * 8, 256);
    int2* cpair = (int2*)p;    p += align_up((size_t)E * 8, 256);
    _Float16* Wt1 = (_Float16*)p; p += align_up((size_t)128 * 128 * 2, 256);
    _Float16* Wt2 = (_Float16*)p; p += align_up((size_t)64 * 128 * 2, 256);
    __half* xw = (__half*)p;   p += align_up((size_t)n * DHID * 2, 256);
    __half* h1 = (__half*)p;   p += align_up((size_t)n * DHID * 2, 256);
    __half* hw2 = xw;  // reuse: xw dead after agg1 (hw needs n*64*2 <= n*128*2)

    hipMemsetAsync(btot, 0, (size_t)nbuck * 4, stream);
    k_prep<<<nblka + 96, 256, 0, stream>>>(esrc, dir, btot, E, nbuck, nblka, W1, W2, Wt1, Wt2);
    k_g1ds<<<ng1 + nbuck, 256, 0, stream>>>(x, Wt1, xw, n, ng1, dir, btot, bucketbase, off,
                                            nbuck, nblka, E);
    k_binwrite<<<nblka, 256, 0, stream>>>(esrc, edst, evalv, dir, ctmp, E, nbuck, nblka);
    k_csrify<<<nbuck, 256, 0, stream>>>(bucketbase, ctmp, cpair, off, n);
    k_agg1<<<(n + 3) / 4, 256, 0, stream>>>(xw, off, cpair, h1, n);
    k_gemm2<<<(n + 63) / 64, 256, 0, stream>>>(h1, Wt2, hw2, n);
    k_agg2<<<(n + 3) / 4, 256, 0, stream>>>(hw2, off, cpair, (float*)d_out, n);
}